// Round 3
// baseline (855.762 us; speedup 1.0000x reference)
//
#include <hip/hip_runtime.h>
#include <stdint.h>

// Problem constants
#define S_DIM 2048
#define B_DIM 4
#define D_DIM 1024
#define E_DIM 8
#define C_DIM 2048
#define FF_DIM 4096
#define N_DIM (S_DIM * B_DIM)  // 8192 tokens

typedef unsigned short u16;
using bf16x8 = __attribute__((ext_vector_type(8))) __bf16;
using u16x8  = __attribute__((ext_vector_type(8))) unsigned short;
using f32x4  = __attribute__((ext_vector_type(4))) float;

// ---------- helpers ----------
__device__ __forceinline__ u16 f2bf(float f) {       // RNE fp32 -> bf16 bits
  uint32_t u = __float_as_uint(f);
  u += 0x7fffu + ((u >> 16) & 1u);
  return (u16)(u >> 16);
}
__device__ __forceinline__ float bf2f(u16 h) {
  return __uint_as_float(((uint32_t)h) << 16);
}
__device__ __forceinline__ void split2(float v, u16& hi, u16& lo) {
  hi = f2bf(v);
  lo = f2bf(v - bf2f(hi));
}
__device__ __forceinline__ float gelu_tanh(float x) {  // jax.nn.gelu approximate=True
  float u = 0.7978845608028654f * (x + 0.044715f * x * x * x);
  return 0.5f * x * (1.0f + tanhf(u));
}
// async global->LDS, 16B per lane. LDS dest = wave-uniform base + lane*16.
__device__ __forceinline__ void cp16(const void* g, void* l) {
  __builtin_amdgcn_global_load_lds(
      (const __attribute__((address_space(1))) void*)g,
      (__attribute__((address_space(3))) void*)l,
      16, 0, 0);
}

// ---------- dtype detector ----------
// If top_idx is really int64 (LE) with values in [0, 8192), every odd int32
// word is zero. If it is int32, odd words are token ids (all-zero ~impossible).
// flag stays 0 -> treat as int64; flag==1 -> int32.
__global__ __launch_bounds__(256) void detect_i64_kernel(
    const int* __restrict__ t, int* __restrict__ flag) {
  int i = blockIdx.x * 256 + threadIdx.x;           // i < E*C/2 = 8192
  if (i < (E_DIM * C_DIM) / 2 && t[2 * i + 1] != 0) atomicOr(flag, 1);
}

// ---------- prep kernels ----------
// tok32[e*C+c] = top_idx[c][e]; wg[e*C+c] = combine_weights[tok][e]
__global__ __launch_bounds__(256) void prep_tok_kernel(
    const void* __restrict__ top_idx, const float* __restrict__ cw,
    const int* __restrict__ flag, int* __restrict__ tok32, float* __restrict__ wg) {
  int t = blockIdx.x * 256 + threadIdx.x;
  if (t >= E_DIM * C_DIM) return;
  int e = t / C_DIM, c = t % C_DIM;
  int tid;
  if (*flag == 0) {  // int64 layout
    tid = (int)((const long long*)top_idx)[(size_t)c * E_DIM + e];
  } else {           // int32 layout
    tid = ((const int*)top_idx)[(size_t)c * E_DIM + e];
  }
  tid &= (N_DIM - 1);  // safety clamp (values are in [0, N))
  tok32[t] = tid;
  wg[t] = cw[(size_t)tid * E_DIM + e];
}

// split x [N][D] fp32 -> bf16 hi/lo
__global__ __launch_bounds__(256) void split_x_kernel(
    const float* __restrict__ x, u16* __restrict__ xh, u16* __restrict__ xl, int wlo) {
  size_t i = ((size_t)blockIdx.x * 256 + threadIdx.x) * 8;
  const float4* p = (const float4*)(x + i);
  float4 v0 = p[0], v1 = p[1];
  float vv[8] = {v0.x, v0.y, v0.z, v0.w, v1.x, v1.y, v1.z, v1.w};
  u16x8 hv, lv;
#pragma unroll
  for (int j = 0; j < 8; ++j) { u16 h, l; split2(vv[j], h, l); hv[j] = h; lv[j] = l; }
  *(u16x8*)(xh + i) = hv;
  if (wlo) *(u16x8*)(xl + i) = lv;
}

// per-expert transpose + split: in [E][R][Cc] fp32 -> out [E][Cc][R] bf16 hi/lo
// Loads coalesced via LDS 64x64 tile; stores vectorized u16x8 (16 B/lane).
__global__ __launch_bounds__(256) void trans_split_kernel(
    const float* __restrict__ in, u16* __restrict__ ohi, u16* __restrict__ olo,
    int R, int Cc, int wlo) {
  __shared__ float T[64][65];
  const int e = blockIdx.z;
  const int c0 = blockIdx.x * 64, r0 = blockIdx.y * 64;
  const int tx = threadIdx.x & 63, ty = threadIdx.x >> 6;
  const float* ein = in + (size_t)e * R * Cc;
  u16* eh = ohi + (size_t)e * R * Cc;
  u16* elo = wlo ? (olo + (size_t)e * R * Cc) : nullptr;
#pragma unroll
  for (int i = 0; i < 16; ++i) {
    int r = ty + i * 4;
    T[r][tx] = ein[(size_t)(r0 + r) * Cc + (c0 + tx)];
  }
  __syncthreads();
  const int tr = (threadIdx.x & 7) * 8;   // 8-elem chunk along transposed-contig dim
  const int cbase = threadIdx.x >> 3;     // 0..31
#pragma unroll
  for (int i = 0; i < 2; ++i) {
    const int c = cbase + i * 32;
    u16x8 hv, lv;
#pragma unroll
    for (int j = 0; j < 8; ++j) {
      u16 h, l; split2(T[tr + j][c], h, l);
      hv[j] = h; lv[j] = l;
    }
    const size_t o = (size_t)(c0 + c) * R + (r0 + tr);  // 16B-aligned
    *(u16x8*)(eh + o) = hv;
    if (wlo) *(u16x8*)(elo + o) = lv;
  }
}

// ---------- GEMM1: h[e][c][f] = gelu(x[tok[e,c]][:] . W1t[e][f][:] + b1[e][f]) ----------
// 128x128 tile, BK=32, 4 waves, 16x16x32 bf16 MFMA, hi/lo 3-product fp32 emulation.
template <bool LOB>
__global__ __launch_bounds__(256) void gemm1_kernel(
    const u16* __restrict__ xs_hi, const u16* __restrict__ xs_lo,
    const u16* __restrict__ w1t_hi, const u16* __restrict__ w1t_lo,
    const int* __restrict__ tok32, const float* __restrict__ b1,
    u16* __restrict__ h_hi, u16* __restrict__ h_lo) {
  __shared__ u16 As_hi[4096], Bs_hi[4096];
  __shared__ u16 As_lo[LOB ? 4096 : 4], Bs_lo[LOB ? 4096 : 4];
  __shared__ int tok_s[128];

  const int e = blockIdx.z, cb = blockIdx.y, fb = blockIdx.x;
  const int t = threadIdx.x, lane = t & 63, w = t >> 6;
  const int wm = w >> 1, wn = w & 1;

  if (t < 128) tok_s[t] = tok32[e * C_DIM + cb * 128 + t];
  __syncthreads();

  // per-thread global staging pointers (gather fused into A staging)
  const u16 *sAh[2], *sAl[2], *sBh[2], *sBl[2];
#pragma unroll
  for (int i = 0; i < 2; ++i) {
    const int q = i * 256 + t, row = q >> 2, sub = q & 3;
    const size_t arow = (size_t)tok_s[row] * D_DIM + sub * 8;  // gathered token row
    sAh[i] = xs_hi + arow;
    if constexpr (LOB) sAl[i] = xs_lo + arow;
    const size_t brow = ((size_t)(e * FF_DIM + fb * 128 + row)) * D_DIM + sub * 8;
    sBh[i] = w1t_hi + brow;
    if constexpr (LOB) sBl[i] = w1t_lo + brow;
  }

  int aOff[4], bOff[4];
#pragma unroll
  for (int mi = 0; mi < 4; ++mi)
    aOff[mi] = (wm * 64 + mi * 16 + (lane & 15)) * 32 + (lane >> 4) * 8;
#pragma unroll
  for (int ni = 0; ni < 4; ++ni)
    bOff[ni] = (wn * 64 + ni * 16 + (lane & 15)) * 32 + (lane >> 4) * 8;

  f32x4 zero = {0.f, 0.f, 0.f, 0.f};
  f32x4 acc[4][4];
#pragma unroll
  for (int mi = 0; mi < 4; ++mi)
#pragma unroll
    for (int ni = 0; ni < 4; ++ni) acc[mi][ni] = zero;

  const int wbase = w * 64 * 8;  // wave-uniform LDS element base

  for (int kk = 0; kk < D_DIM / 32; ++kk) {
    const int ke = kk * 32;
#pragma unroll
    for (int i = 0; i < 2; ++i) {
      const int lofs = i * 2048 + wbase;
      cp16(sAh[i] + ke, &As_hi[lofs]);
      cp16(sBh[i] + ke, &Bs_hi[lofs]);
      if constexpr (LOB) {
        cp16(sAl[i] + ke, &As_lo[lofs]);
        cp16(sBl[i] + ke, &Bs_lo[lofs]);
      }
    }
    __syncthreads();

    bf16x8 ah[4], bh[4], al[4], bl[4];
#pragma unroll
    for (int mi = 0; mi < 4; ++mi) {
      ah[mi] = *(const bf16x8*)&As_hi[aOff[mi]];
      if constexpr (LOB) al[mi] = *(const bf16x8*)&As_lo[aOff[mi]];
    }
#pragma unroll
    for (int ni = 0; ni < 4; ++ni) {
      bh[ni] = *(const bf16x8*)&Bs_hi[bOff[ni]];
      if constexpr (LOB) bl[ni] = *(const bf16x8*)&Bs_lo[bOff[ni]];
    }
#pragma unroll
    for (int mi = 0; mi < 4; ++mi)
#pragma unroll
      for (int ni = 0; ni < 4; ++ni) {
        acc[mi][ni] = __builtin_amdgcn_mfma_f32_16x16x32_bf16(ah[mi], bh[ni], acc[mi][ni], 0, 0, 0);
        if constexpr (LOB) {
          acc[mi][ni] = __builtin_amdgcn_mfma_f32_16x16x32_bf16(ah[mi], bl[ni], acc[mi][ni], 0, 0, 0);
          acc[mi][ni] = __builtin_amdgcn_mfma_f32_16x16x32_bf16(al[mi], bh[ni], acc[mi][ni], 0, 0, 0);
        }
      }
    __syncthreads();
  }

  // epilogue: bias + gelu, split to bf16 hi/lo, store h
  const int c_base0 = cb * 128 + wm * 64;
  const int f_base0 = fb * 128 + wn * 64;
#pragma unroll
  for (int ni = 0; ni < 4; ++ni) {
    const int f = f_base0 + ni * 16 + (lane & 15);
    const float bias = b1[e * FF_DIM + f];
#pragma unroll
    for (int mi = 0; mi < 4; ++mi) {
#pragma unroll
      for (int j = 0; j < 4; ++j) {
        const int c = c_base0 + mi * 16 + (lane >> 4) * 4 + j;
        float g = gelu_tanh(acc[mi][ni][j] + bias);
        u16 hh, ll; split2(g, hh, ll);
        const size_t off = ((size_t)(e * C_DIM + c)) * FF_DIM + f;
        h_hi[off] = hh;
        if constexpr (LOB) h_lo[off] = ll;
      }
    }
  }
}

// ---------- GEMM2: out[tok] += w * (h[e][c][:] . W2t[e][d][:] + b2[e][d]) ----------
template <bool LOB>
__global__ __launch_bounds__(256) void gemm2_kernel(
    const u16* __restrict__ h_hi, const u16* __restrict__ h_lo,
    const u16* __restrict__ w2t_hi, const u16* __restrict__ w2t_lo,
    const int* __restrict__ tok32, const float* __restrict__ wg,
    const float* __restrict__ b2, float* __restrict__ out) {
  __shared__ u16 As_hi[4096], Bs_hi[4096];
  __shared__ u16 As_lo[LOB ? 4096 : 4], Bs_lo[LOB ? 4096 : 4];
  __shared__ int tok_s[128];
  __shared__ float w_s[128];

  const int e = blockIdx.z, cb = blockIdx.y, db = blockIdx.x;
  const int t = threadIdx.x, lane = t & 63, w = t >> 6;
  const int wm = w >> 1, wn = w & 1;

  if (t < 128) {
    tok_s[t] = tok32[e * C_DIM + cb * 128 + t];
    w_s[t] = wg[e * C_DIM + cb * 128 + t];
  }
  // tok_s/w_s only read in the epilogue (after the k-loop's barriers)

  const u16 *sAh[2], *sAl[2], *sBh[2], *sBl[2];
#pragma unroll
  for (int i = 0; i < 2; ++i) {
    const int q = i * 256 + t, row = q >> 2, sub = q & 3;
    const size_t arow = ((size_t)(e * C_DIM + cb * 128 + row)) * FF_DIM + sub * 8;
    sAh[i] = h_hi + arow;
    if constexpr (LOB) sAl[i] = h_lo + arow;
    const size_t brow = ((size_t)(e * D_DIM + db * 128 + row)) * FF_DIM + sub * 8;
    sBh[i] = w2t_hi + brow;
    if constexpr (LOB) sBl[i] = w2t_lo + brow;
  }

  int aOff[4], bOff[4];
#pragma unroll
  for (int mi = 0; mi < 4; ++mi)
    aOff[mi] = (wm * 64 + mi * 16 + (lane & 15)) * 32 + (lane >> 4) * 8;
#pragma unroll
  for (int ni = 0; ni < 4; ++ni)
    bOff[ni] = (wn * 64 + ni * 16 + (lane & 15)) * 32 + (lane >> 4) * 8;

  f32x4 zero = {0.f, 0.f, 0.f, 0.f};
  f32x4 acc[4][4];
#pragma unroll
  for (int mi = 0; mi < 4; ++mi)
#pragma unroll
    for (int ni = 0; ni < 4; ++ni) acc[mi][ni] = zero;

  const int wbase = w * 64 * 8;

  for (int kk = 0; kk < FF_DIM / 32; ++kk) {
    const int ke = kk * 32;
#pragma unroll
    for (int i = 0; i < 2; ++i) {
      const int lofs = i * 2048 + wbase;
      cp16(sAh[i] + ke, &As_hi[lofs]);
      cp16(sBh[i] + ke, &Bs_hi[lofs]);
      if constexpr (LOB) {
        cp16(sAl[i] + ke, &As_lo[lofs]);
        cp16(sBl[i] + ke, &Bs_lo[lofs]);
      }
    }
    __syncthreads();

    bf16x8 ah[4], bh[4], al[4], bl[4];
#pragma unroll
    for (int mi = 0; mi < 4; ++mi) {
      ah[mi] = *(const bf16x8*)&As_hi[aOff[mi]];
      if constexpr (LOB) al[mi] = *(const bf16x8*)&As_lo[aOff[mi]];
    }
#pragma unroll
    for (int ni = 0; ni < 4; ++ni) {
      bh[ni] = *(const bf16x8*)&Bs_hi[bOff[ni]];
      if constexpr (LOB) bl[ni] = *(const bf16x8*)&Bs_lo[bOff[ni]];
    }
#pragma unroll
    for (int mi = 0; mi < 4; ++mi)
#pragma unroll
      for (int ni = 0; ni < 4; ++ni) {
        acc[mi][ni] = __builtin_amdgcn_mfma_f32_16x16x32_bf16(ah[mi], bh[ni], acc[mi][ni], 0, 0, 0);
        if constexpr (LOB) {
          acc[mi][ni] = __builtin_amdgcn_mfma_f32_16x16x32_bf16(ah[mi], bl[ni], acc[mi][ni], 0, 0, 0);
          acc[mi][ni] = __builtin_amdgcn_mfma_f32_16x16x32_bf16(al[mi], bh[ni], acc[mi][ni], 0, 0, 0);
        }
      }
    __syncthreads();
  }

  // epilogue: bias, gate weight, scatter-add combine
  const int dbase = db * 128 + wn * 64;
#pragma unroll
  for (int ni = 0; ni < 4; ++ni) {
    const int d = dbase + ni * 16 + (lane & 15);
    const float bias = b2[e * D_DIM + d];
#pragma unroll
    for (int mi = 0; mi < 4; ++mi) {
#pragma unroll
      for (int j = 0; j < 4; ++j) {
        const int cl = wm * 64 + mi * 16 + (lane >> 4) * 4 + j;
        const float val = (acc[mi][ni][j] + bias) * w_s[cl];
        atomicAdd(out + (size_t)tok_s[cl] * D_DIM + d, val);
      }
    }
  }
}

// ---------- launch ----------
extern "C" void kernel_launch(void* const* d_in, const int* in_sizes, int n_in,
                              void* d_out, int out_size, void* d_ws, size_t ws_size,
                              hipStream_t stream) {
  (void)in_sizes; (void)n_in; (void)out_size;
  const float* x  = (const float*)d_in[0];
  const float* cw = (const float*)d_in[1];
  const void* tidx = d_in[2];              // int32 or int64 — detected on device
  const float* W1 = (const float*)d_in[3];
  const float* b1 = (const float*)d_in[4];
  const float* W2 = (const float*)d_in[5];
  const float* b2 = (const float*)d_in[6];
  float* out = (float*)d_out;

  const size_t nx  = (size_t)N_DIM * D_DIM;           // 8.39M
  const size_t nw  = (size_t)E_DIM * FF_DIM * D_DIM;  // 33.6M
  const size_t nh  = (size_t)E_DIM * C_DIM * FF_DIM;  // 67.1M
  const size_t nEC = (size_t)E_DIM * C_DIM;

  const size_t need_hi   = (nx + 2 * nw + nh) * 2 + nEC * 8 + 64;  // ~285 MB
  const size_t need_full = (nx + 2 * nw + nh) * 4 + nEC * 8 + 64;  // ~571 MB

  const bool lo = ws_size >= need_full;
  if (!lo && ws_size < need_hi) return;  // cannot run in this workspace

  char* p = (char*)d_ws;
  auto take = [&](size_t bytes) { char* r = p; p += bytes; return r; };
  u16* xs_hi  = (u16*)take(nx * 2);
  u16* xs_lo  = lo ? (u16*)take(nx * 2) : nullptr;
  u16* w1t_hi = (u16*)take(nw * 2);
  u16* w1t_lo = lo ? (u16*)take(nw * 2) : nullptr;
  u16* w2t_hi = (u16*)take(nw * 2);
  u16* w2t_lo = lo ? (u16*)take(nw * 2) : nullptr;
  u16* h_hi   = (u16*)take(nh * 2);
  u16* h_lo   = lo ? (u16*)take(nh * 2) : nullptr;
  int*  tok32 = (int*)take(nEC * 4);
  float* wg   = (float*)take(nEC * 4);
  int*  flag  = (int*)take(64);

  hipMemsetAsync(d_out, 0, nx * sizeof(float), stream);
  hipMemsetAsync(flag, 0, sizeof(int), stream);
  detect_i64_kernel<<<(int)((nEC / 2 + 255) / 256), 256, 0, stream>>>((const int*)tidx, flag);
  prep_tok_kernel<<<(int)((nEC + 255) / 256), 256, 0, stream>>>(tidx, cw, flag, tok32, wg);
  split_x_kernel<<<(int)(nx / 8 / 256), 256, 0, stream>>>(x, xs_hi, xs_lo, lo ? 1 : 0);
  trans_split_kernel<<<dim3(FF_DIM / 64, D_DIM / 64, E_DIM), 256, 0, stream>>>(
      W1, w1t_hi, w1t_lo, D_DIM, FF_DIM, lo ? 1 : 0);
  trans_split_kernel<<<dim3(D_DIM / 64, FF_DIM / 64, E_DIM), 256, 0, stream>>>(
      W2, w2t_hi, w2t_lo, FF_DIM, D_DIM, lo ? 1 : 0);

  const dim3 g1(FF_DIM / 128, C_DIM / 128, E_DIM);  // 32 x 16 x 8
  const dim3 g2(D_DIM / 128, C_DIM / 128, E_DIM);   // 8 x 16 x 8
  if (lo) {
    gemm1_kernel<true><<<g1, 256, 0, stream>>>(xs_hi, xs_lo, w1t_hi, w1t_lo, tok32, b1, h_hi, h_lo);
    gemm2_kernel<true><<<g2, 256, 0, stream>>>(h_hi, h_lo, w2t_hi, w2t_lo, tok32, wg, b2, out);
  } else {
    gemm1_kernel<false><<<g1, 256, 0, stream>>>(xs_hi, nullptr, w1t_hi, nullptr, tok32, b1, h_hi, nullptr);
    gemm2_kernel<false><<<g2, 256, 0, stream>>>(h_hi, nullptr, w2t_hi, nullptr, tok32, wg, b2, out);
  }
}